// Round 5
// baseline (280.205 us; speedup 1.0000x reference)
//
#include <hip/hip_runtime.h>

// DeltaModulationEncoder: x (16, 256, 8192) f32 -> spikes {-1,0,1} f32.
// Exact monolithic scan (recurrence is serial per channel).
// 256 blocks x 1 wave; 16 channels/block (lanes 0-15 compute, all 64 lanes
// drive DMA). Per 128-step tile:
//   - 8 x 1024B global_load_lds (16B/lane), double-buffered; source-side XOR
//     swizzle, read-side applies the same involution (rule #21) -> 0 bank
//     conflicts (verified round 4).
//   - counted s_waitcnt vmcnt(32): waits only for the 8 oldest ops (the DMA
//     loads of this tile); never drains the 32 younger in-flight stores.
//   - 3-deep chunk register pipeline on ds_read_b128: each chunk's load is
//     issued 2 chunks (~150 cyc of compute) before first use.
//   - 16-cyc dependent chain/step: rp/rm precomputed off-chain, chain is
//     sub -> cmp -> cndmask -> cndmask; spike sels off-chain.

constexpr float TH     = 0.1f;
constexpr int   T      = 8192;
constexpr int   NCH    = 4096;
constexpr int   CPB    = 16;             // channels per block
constexpr int   NBLK   = NCH / CPB;      // 256 blocks (one per CU)
constexpr int   TILE   = 128;            // timesteps per staged tile
constexpr int   NTILE  = T / TILE;       // 64
constexpr int   NCHUNK = TILE / 4;       // 32 x 16B chunks per row-tile

typedef __attribute__((address_space(1))) const float gfloat;
typedef __attribute__((address_space(3))) float       lfloat;

__device__ __forceinline__ void gload_lds16(const void* g, void* l) {
    __builtin_amdgcn_global_load_lds((const gfloat*)g, (lfloat*)l, 16, 0, 0);
}

// Bit-exact reference step. Reference: err = x - recon; net = (err>th)-(err<-th);
// recon += net*th; spike = net. net*th is exactly {+0.1f, -0.1f, +0.0f}, so
// recon_next is exactly one of {fl(recon+0.1f), fl(recon-0.1f), recon}
// (recon is never -0.0f: fl-sums of +-0.1f quanta can only produce +0.0f, so
// the net==0 case recon+0.0f == recon bitwise). rp/rm are those two sums,
// computed OFF the dependency chain; the chain is sub->cmp->sel->sel = 16 cyc.
// Spikes are selected directly as {-1.0f, 0.0f, 1.0f} inline constants.
// No mul feeds an add anywhere -> FMA contraction cannot change rounding.
__device__ __forceinline__ void dm_step(float xv, float& recon, float& spike) {
    float rp  = recon + TH;     // off-chain
    float rm  = recon - TH;     // off-chain
    float err = xv - recon;     // chain
    bool  c1  = err > TH;       // chain (c1, c2 issue back-to-back, parallel deps)
    bool  c2  = err < -TH;
    float rn  = c1 ? rp : recon;   // chain
    rn        = c2 ? rm : rn;      // chain
    float sp  = c1 ? 1.0f : 0.0f;  // off-chain
    spike     = c2 ? -1.0f : sp;   // off-chain
    recon     = rn;
}

__global__ __launch_bounds__(64) void dm_scan(const float* __restrict__ x,
                                              float* __restrict__ out) {
    __shared__ float xb[2][CPB][TILE];   // 16 KiB, linear (DMA-compatible)
    const int lane   = threadIdx.x;
    const int chBase = blockIdx.x * CPB;

    // Per-lane global byte offsets for the 8 staging DMAs. Instruction i
    // covers rows 2i (lanes 0-31) and 2i+1 (lanes 32-63); LDS slot s of row r
    // receives data chunk c = s ^ (r&7)  (source-side swizzle).
    uint32_t voff[8];
#pragma unroll
    for (int i = 0; i < 8; ++i) {
        int r = 2 * i + (lane >> 5);
        int s = lane & 31;
        int c = s ^ (r & 7);
        voff[i] = (uint32_t)r * (uint32_t)(T * 4) + (uint32_t)c * 16u;
    }
    const char* panel = (const char*)(x + (size_t)chBase * T);

    auto stage = [&](int tt, int b) {
        const char* pt = panel + (size_t)tt * (TILE * 4);
#pragma unroll
        for (int i = 0; i < 8; ++i) {
            gload_lds16(pt + voff[i], &xb[b][2 * i][0]);
        }
    };

    stage(0, 0);
    asm volatile("s_waitcnt vmcnt(0)" ::: "memory");   // prologue only

    float recon = 0.0f;
    const char* lb = (const char*)&xb[0][0][0];
    // Read-side swizzle: chunk c of row `lane` lives at byte (base ^ (c<<4)),
    // base = lane*512 + ((lane&7)<<4) — same involution the DMA source applied.
    const uint32_t swz = (uint32_t)lane * 512u + (uint32_t)((lane & 7) << 4);
    float4* po = (float4*)(out + (size_t)(chBase + (lane & (CPB - 1))) * T);

    for (int tt = 0; tt < NTILE; ++tt) {
        const int b = tt & 1;
        if (tt > 0) {
            // Outstanding (oldest->newest): DMA(tt) x8, stores(tt-1) x32.
            // vmcnt counts in issue order -> vmcnt(32) waits exactly for the
            // 8 DMAs of this tile; stores never block.
            asm volatile("s_waitcnt vmcnt(32)" ::: "memory");
        }
        if (tt + 1 < NTILE) stage(tt + 1, b ^ 1);   // async prefetch, full tile ahead

        if (lane < CPB) {
            const uint32_t blb = swz + (uint32_t)b * (uint32_t)(CPB * TILE * 4);
            auto rd = [&](int c) -> float4 {
                return *(const float4*)(lb + (blb ^ (uint32_t)(c * 16)));
            };
            // 3-deep software pipeline; full unroll -> q[] indices are
            // compile-time (registers, not scratch).
            float4 q[3];
            q[0] = rd(0);
            q[1] = rd(1);
            float4* pot = po + (size_t)tt * NCHUNK;
#pragma unroll
            for (int c = 0; c < NCHUNK; ++c) {
                float4 xv = q[c % 3];
                if (c + 2 < NCHUNK) q[(c + 2) % 3] = rd(c + 2);
                float4 s;
                dm_step(xv.x, recon, s.x);
                dm_step(xv.y, recon, s.y);
                dm_step(xv.z, recon, s.z);
                dm_step(xv.w, recon, s.w);
                pot[c] = s;   // fire-and-forget
            }
        }
    }
}

extern "C" void kernel_launch(void* const* d_in, const int* in_sizes, int n_in,
                              void* d_out, int out_size, void* d_ws, size_t ws_size,
                              hipStream_t stream) {
    const float* x   = (const float*)d_in[0];
    float*       out = (float*)d_out;
    dm_scan<<<NBLK, 64, 0, stream>>>(x, out);
}